// Round 1
// baseline (2104.072 us; speedup 1.0000x reference)
//
#include <hip/hip_runtime.h>
#include <math.h>

namespace {
constexpr int kNE = 512;          // num codebook entries
constexpr int kED = 64;           // embed dim
constexpr int kHW = 4096;         // 64*64 spatial
constexpr int kNTok = 131072;     // 32*64*64 tokens
constexpr int kTokPerBlk = 64;
constexpr int kThreads = 256;
constexpr int kChunk = 128;       // codes per LDS chunk

// output float offsets (return order: loss, out, perplexity, encodings,
// new_embedding, cluster, new_ema_w)
constexpr size_t O_LOSS    = 0;
constexpr size_t O_OUT     = 1;
constexpr size_t O_PERP    = 8388609;
constexpr size_t O_ENC     = 8388610;
constexpr size_t O_NEWEMB  = 75497474;
constexpr size_t O_CLUSTER = 75530242;
constexpr size_t O_NEWEMAW = 75530754;

// workspace float offsets
constexpr size_t W_COUNTS = 0;        // 512 floats
constexpr size_t W_DW     = 512;      // 32768 floats
constexpr size_t W_LOSS   = 33280;    // 1 float
constexpr size_t W_SE32   = 33284;    // 512 floats
constexpr size_t W_SE64B  = 135184;   // byte offset, 512 doubles (8B aligned)

constexpr float kMargin = 5e-3f;      // fp32 gap below which we fp64-rescan
}

// Precompute ||e_j||^2 in fp64 (exact ref for rescan) and fp32 (fast path).
extern "C" __global__ void vq_se(const float* __restrict__ emb,
                                 float* __restrict__ se32,
                                 double* __restrict__ se64) {
  int j = blockIdx.x * blockDim.x + threadIdx.x;
  if (j >= kNE) return;
  const float* e = emb + (size_t)j * kED;
  double s = 0.0;
  #pragma unroll
  for (int d = 0; d < kED; ++d) { double v = (double)e[d]; s += v * v; }
  se64[j] = s;
  se32[j] = (float)s;
}

extern "C" __global__ __launch_bounds__(kThreads) void vq_main(
    const float* __restrict__ x, const float* __restrict__ emb,
    const float* __restrict__ se32, const double* __restrict__ se64,
    float* __restrict__ out_q, float* __restrict__ enc,
    float* __restrict__ counts, float* __restrict__ dw,
    float* __restrict__ loss_sum) {
  __shared__ float flat[kTokPerBlk][65];   // token-major x tile (stride 65: 2-way max)
  __shared__ float etile[kChunk][68];      // code chunk (stride 68: 4-row reads conflict-free)
  __shared__ float se_t[kChunk];
  __shared__ float redv[kThreads];
  __shared__ float redv2[kThreads];
  __shared__ int   redi[kThreads];
  __shared__ double redd[kThreads];
  __shared__ int   redj[kThreads];
  __shared__ int   tok_idx[kTokPerBlk];
  __shared__ int   flag_list[kTokPerBlk];
  __shared__ int   flag_cnt;

  const int tid = threadIdx.x;
  const int token_base = blockIdx.x * kTokPerBlk;
  const int batch = token_base / kHW;
  const int pos0  = token_base % kHW;   // tiles never cross batch (4096 % 64 == 0)

  if (tid == 0) flag_cnt = 0;

  // ---- stage x tile (transpose NCHW -> token-major) ----
  const float* xb = x + (size_t)batch * kED * kHW + pos0;
  {
    const int p  = tid & 63;
    const int d0 = tid >> 6;
    #pragma unroll
    for (int i = 0; i < 16; ++i) {
      int d = i * 4 + d0;
      flat[p][d] = xb[(size_t)d * kHW + p];   // coalesced 64-float rows
    }
  }
  __syncthreads();

  // ---- per-thread token registers (4 threads share a token) ----
  const int r = tid >> 2;
  const int a = tid & 3;
  float fr[kED];
  #pragma unroll
  for (int d = 0; d < kED; ++d) fr[d] = flat[r][d];
  float s_f = 0.f;
  #pragma unroll
  for (int d = 0; d < kED; ++d) s_f = __builtin_fmaf(fr[d], fr[d], s_f);

  float best = INFINITY, second = INFINITY;
  int bestj = 0;

  // ---- fp32 distance scan over 4 chunks of 128 codes ----
  for (int c0 = 0; c0 < kNE; c0 += kChunk) {
    __syncthreads();
    {
      const float4* src = (const float4*)(emb + (size_t)c0 * kED);
      #pragma unroll
      for (int i = 0; i < 8; ++i) {
        int q = i * kThreads + tid;       // float4 idx, 0..2047
        int row = q >> 4;
        int c4  = (q & 15) << 2;
        float4 v = src[q];
        *(float4*)&etile[row][c4] = v;
      }
      if (tid < kChunk) se_t[tid] = se32[c0 + tid];
    }
    __syncthreads();

    #pragma unroll 2
    for (int i = 0; i < 16; ++i) {
      int jl0 = a + i * 8;     // thread a owns codes == a (mod 4): j increasing
      int jl1 = jl0 + 4;
      const float* e0 = &etile[jl0][0];
      const float* e1 = &etile[jl1][0];
      float d00=0.f,d01=0.f,d02=0.f,d03=0.f;
      float d10=0.f,d11=0.f,d12=0.f,d13=0.f;
      #pragma unroll
      for (int dq = 0; dq < 16; ++dq) {
        float4 u = *(const float4*)&e0[dq*4];
        float4 w = *(const float4*)&e1[dq*4];
        d00 = __builtin_fmaf(fr[dq*4+0], u.x, d00);
        d01 = __builtin_fmaf(fr[dq*4+1], u.y, d01);
        d02 = __builtin_fmaf(fr[dq*4+2], u.z, d02);
        d03 = __builtin_fmaf(fr[dq*4+3], u.w, d03);
        d10 = __builtin_fmaf(fr[dq*4+0], w.x, d10);
        d11 = __builtin_fmaf(fr[dq*4+1], w.y, d11);
        d12 = __builtin_fmaf(fr[dq*4+2], w.z, d12);
        d13 = __builtin_fmaf(fr[dq*4+3], w.w, d13);
      }
      float dot0 = (d00 + d01) + (d02 + d03);
      float dot1 = (d10 + d11) + (d12 + d13);
      float dist0 = s_f + se_t[jl0] - 2.f * dot0;
      float dist1 = s_f + se_t[jl1] - 2.f * dot1;
      if (dist0 < best) { second = best; best = dist0; bestj = c0 + jl0; }
      else second = fminf(second, dist0);
      if (dist1 < best) { second = best; best = dist1; bestj = c0 + jl1; }
      else second = fminf(second, dist1);
    }
  }

  redv[tid] = best; redv2[tid] = second; redi[tid] = bestj;
  __syncthreads();

  // ---- merge 4 threads per token; flag near-ties for fp64 rescan ----
  if (tid < kTokPerBlk) {
    float bv = redv[tid*4]; int bj = redi[tid*4]; float sv = redv2[tid*4];
    #pragma unroll
    for (int t = 1; t < 4; ++t) {
      float v = redv[tid*4+t]; int j = redi[tid*4+t]; float s2 = redv2[tid*4+t];
      if (v < bv || (v == bv && j < bj)) {
        sv = fminf(fminf(bv, s2), sv);
        bv = v; bj = j;
      } else {
        sv = fminf(sv, fminf(v, s2));
      }
    }
    tok_idx[tid] = bj;
    if (sv - bv < kMargin) {
      int p = atomicAdd(&flag_cnt, 1);
      flag_list[p] = tid;
    }
  }
  __syncthreads();

  // ---- exact fp64 rescan for flagged tokens (rare; whole block cooperates) ----
  const int nflag = flag_cnt;
  for (int fi = 0; fi < nflag; ++fi) {
    const int tr = flag_list[fi];
    double db = 1e300; int dbj = 0;
    #pragma unroll 1
    for (int jj = 0; jj < 2; ++jj) {
      int j = tid * 2 + jj;
      const float* er = emb + (size_t)j * kED;
      double dot = 0.0;
      #pragma unroll 1
      for (int d = 0; d < kED; ++d)
        dot = __builtin_fma((double)flat[tr][d], (double)er[d], dot);
      double dist = se64[j] - 2.0 * dot;   // s_f is token-constant: drop
      if (dist < db || (dist == db && j < dbj)) { db = dist; dbj = j; }
    }
    redd[tid] = db; redj[tid] = dbj;
    __syncthreads();
    for (int s2 = kThreads / 2; s2 > 0; s2 >>= 1) {
      if (tid < s2) {
        double v = redd[tid + s2]; int j = redj[tid + s2];
        if (v < redd[tid] || (v == redd[tid] && j < redj[tid])) {
          redd[tid] = v; redj[tid] = j;
        }
      }
      __syncthreads();
    }
    if (tid == 0) tok_idx[tr] = redj[0];
    __syncthreads();
  }

  // ---- cluster counts ----
  if (tid < kTokPerBlk) atomicAdd(&counts[tok_idx[tid]], 1.0f);

  // ---- encodings one-hot: write computed values directly (no zero/set race) ----
  {
    float2* encb2 = (float2*)(enc + (size_t)token_base * kNE);
    #pragma unroll 4
    for (int i = 0; i < 64; ++i) {
      int q = i * kThreads + tid;   // float2 idx, 0..16383
      int row = q >> 8;             // 256 float2 per token row
      int c2  = (q & 255) * 2;
      int bi = tok_idx[row];
      float2 v;
      v.x = (bi == c2)     ? 1.f : 0.f;
      v.y = (bi == c2 + 1) ? 1.f : 0.f;
      encb2[q] = v;
    }
  }

  // ---- gather assigned code rows into LDS (reuse etile) ----
  float* qt = &etile[0][0];   // [64][65] overlay
  {
    int rr = tid >> 2;
    int c0 = (tid & 3) * 16;
    const float* er = emb + (size_t)tok_idx[rr] * kED;
    #pragma unroll
    for (int i = 0; i < 16; ++i) qt[rr * 65 + c0 + i] = er[c0 + i];
  }
  __syncthreads();

  // ---- quantized_st output (coalesced NCHW) + commitment loss ----
  float lacc = 0.f;
  {
    float* outb = out_q + (size_t)batch * kED * kHW + pos0;
    const int p  = tid & 63;
    const int c0 = tid >> 6;
    #pragma unroll
    for (int i = 0; i < 16; ++i) {
      int c = i * 4 + c0;
      float inv  = flat[p][c];
      float qv   = qt[p * 65 + c];
      float diff = qv - inv;
      outb[(size_t)c * kHW + p] = inv + diff;   // straight-through, ref's fp order
      lacc = __builtin_fmaf(diff, diff, lacc);
    }
  }
  #pragma unroll
  for (int off = 32; off > 0; off >>= 1) lacc += __shfl_down(lacc, off, 64);
  if ((tid & 63) == 0) atomicAdd(loss_sum, lacc);

  // ---- dw scatter: dw[idx][d] += flat[token][d] ----
  {
    int rr = tid >> 2;
    int c0 = (tid & 3) * 16;
    float* dwr = dw + (size_t)tok_idx[rr] * kED;
    #pragma unroll
    for (int i = 0; i < 16; ++i) atomicAdd(&dwr[c0 + i], flat[rr][c0 + i]);
  }
}

// cluster Laplace smoothing, perplexity, loss
extern "C" __global__ void vq_fin_a(const float* __restrict__ ema_cs,
                                    const float* __restrict__ counts,
                                    const float* __restrict__ loss_sum,
                                    float* __restrict__ out) {
  __shared__ float red[kNE];
  const int j = threadIdx.x;
  float craw = ema_cs[j] * 0.99f + 0.01f * counts[j];
  red[j] = craw;
  __syncthreads();
  for (int s = kNE / 2; s > 0; s >>= 1) {
    if (j < s) red[j] += red[j + s];
    __syncthreads();
  }
  float k = red[0];
  __syncthreads();
  float clu = (craw + 1e-5f) / (k + kNE * 1e-5f) * k;
  out[O_CLUSTER + j] = clu;
  float avg = counts[j] * (1.0f / 131072.0f);
  float term = avg * logf(avg + 1e-10f);
  red[j] = term;
  __syncthreads();
  for (int s = kNE / 2; s > 0; s >>= 1) {
    if (j < s) red[j] += red[j + s];
    __syncthreads();
  }
  if (j == 0) {
    out[O_PERP] = expf(-red[0]);
    out[O_LOSS] = 0.25f * loss_sum[0] * (1.0f / 8388608.0f);
  }
}

// new_ema_w and new_embedding
extern "C" __global__ void vq_fin_b(const float* __restrict__ ema_w,
                                    const float* __restrict__ dw,
                                    const float* __restrict__ out_cluster,
                                    float* __restrict__ out) {
  int i = blockIdx.x * blockDim.x + threadIdx.x;   // 0..32767
  int j = i >> 6;
  float nw = ema_w[i] * 0.99f + 0.01f * dw[i];
  out[O_NEWEMAW + i] = nw;
  out[O_NEWEMB + i] = nw / out_cluster[j];
}

extern "C" void kernel_launch(void* const* d_in, const int* in_sizes, int n_in,
                              void* d_out, int out_size, void* d_ws, size_t ws_size,
                              hipStream_t stream) {
  const float* x      = (const float*)d_in[0];
  const float* emb    = (const float*)d_in[1];
  const float* ema_w  = (const float*)d_in[2];
  const float* ema_cs = (const float*)d_in[3];
  float* out = (float*)d_out;
  float* ws  = (float*)d_ws;

  float*  counts   = ws + W_COUNTS;
  float*  dw       = ws + W_DW;
  float*  loss_sum = ws + W_LOSS;
  float*  se32     = ws + W_SE32;
  double* se64     = (double*)((char*)d_ws + W_SE64B);

  // zero counts + dw + loss (ws is re-poisoned before every launch)
  hipMemsetAsync(d_ws, 0, (W_LOSS + 1) * sizeof(float), stream);
  hipLaunchKernelGGL(vq_se, dim3(2), dim3(256), 0, stream, emb, se32, se64);
  hipLaunchKernelGGL(vq_main, dim3(kNTok / kTokPerBlk), dim3(kThreads), 0, stream,
                     x, emb, se32, se64, out + O_OUT, out + O_ENC,
                     counts, dw, loss_sum);
  hipLaunchKernelGGL(vq_fin_a, dim3(1), dim3(kNE), 0, stream,
                     ema_cs, counts, loss_sum, out);
  hipLaunchKernelGGL(vq_fin_b, dim3(32768 / 256), dim3(256), 0, stream,
                     ema_w, dw, out + O_CLUSTER, out);
}

// Round 2
// 614.807 us; speedup vs baseline: 3.4223x; 3.4223x over previous
//
#include <hip/hip_runtime.h>
#include <math.h>

namespace {
constexpr int kNE = 512;          // num codebook entries
constexpr int kED = 64;           // embed dim
constexpr int kHW = 4096;         // 64*64 spatial
constexpr int kNTok = 131072;     // 32*64*64 tokens
constexpr int kNTiles = 2048;     // 64-token tiles
constexpr int kTokPerBlk = 64;
constexpr int kThreads = 256;
constexpr int kChunk = 128;       // codes per LDS chunk

// output float offsets (return order: loss, out, perplexity, encodings,
// new_embedding, cluster, new_ema_w)
constexpr size_t O_LOSS    = 0;
constexpr size_t O_OUT     = 1;
constexpr size_t O_PERP    = 8388609;
constexpr size_t O_ENC     = 8388610;   // byte-align 8 (float2 ok, float4 NOT)
constexpr size_t O_NEWEMB  = 75497474;
constexpr size_t O_CLUSTER = 75530242;
constexpr size_t O_NEWEMAW = 75530754;

// workspace layout (float offsets unless noted)
constexpr size_t W_IDX   = 0;        // 131072 ints (token -> code)
constexpr size_t W_LOSS  = 131072;   // 1 float
constexpr size_t W_SE32  = 131073;   // 512 floats
constexpr size_t W_SE64  = 131586;   // 512 doubles (byte 526344, 8B aligned)
constexpr size_t W_CNT   = 132610;   // 512 floats (final counts)
constexpr size_t W_DW    = 133122;   // 32768 floats (final dw)
constexpr size_t W_PART  = 165892;   // G x 33280 floats (byte 663568, 16B aligned)
constexpr int    kPartStride = 33280;   // 32768 dw + 512 hist

constexpr float kMargin = 5e-3f;     // fp32 gap below which we fp64-rescan
}

// Precompute ||e_j||^2 in fp64 (exact ref for rescan) and fp32 (fast path).
extern "C" __global__ void vq_se(const float* __restrict__ emb,
                                 float* __restrict__ se32,
                                 double* __restrict__ se64) {
  int j = blockIdx.x * blockDim.x + threadIdx.x;
  if (j >= kNE) return;
  const float* e = emb + (size_t)j * kED;
  double s = 0.0;
  #pragma unroll
  for (int d = 0; d < kED; ++d) { double v = (double)e[d]; s += v * v; }
  se64[j] = s;
  se32[j] = (float)s;
}

extern "C" __global__ __launch_bounds__(kThreads) void vq_main(
    const float* __restrict__ x, const float* __restrict__ emb,
    const float* __restrict__ se32, const double* __restrict__ se64,
    float* __restrict__ out_q, float* __restrict__ enc,
    int* __restrict__ idx_out, float* __restrict__ loss_sum) {
  __shared__ float flat[kTokPerBlk][65];   // token-major x tile
  __shared__ float etile[kChunk][68];      // code chunk
  __shared__ float se_t[kChunk];
  __shared__ float redv[kThreads];
  __shared__ float redv2[kThreads];
  __shared__ int   redi[kThreads];
  __shared__ double redd[kThreads];
  __shared__ int   redj[kThreads];
  __shared__ int   tok_idx[kTokPerBlk];
  __shared__ int   flag_list[kTokPerBlk];
  __shared__ int   flag_cnt;

  const int tid = threadIdx.x;
  const int token_base = blockIdx.x * kTokPerBlk;
  const int batch = token_base / kHW;
  const int pos0  = token_base % kHW;   // tiles never cross batch

  if (tid == 0) flag_cnt = 0;

  // ---- stage x tile (transpose NCHW -> token-major) ----
  const float* xb = x + (size_t)batch * kED * kHW + pos0;
  {
    const int p  = tid & 63;
    const int d0 = tid >> 6;
    #pragma unroll
    for (int i = 0; i < 16; ++i) {
      int d = i * 4 + d0;
      flat[p][d] = xb[(size_t)d * kHW + p];
    }
  }
  __syncthreads();

  // ---- per-thread token registers (4 threads share a token) ----
  const int r = tid >> 2;
  const int a = tid & 3;
  float fr[kED];
  #pragma unroll
  for (int d = 0; d < kED; ++d) fr[d] = flat[r][d];
  float s_f = 0.f;
  #pragma unroll
  for (int d = 0; d < kED; ++d) s_f = __builtin_fmaf(fr[d], fr[d], s_f);

  float best = INFINITY, second = INFINITY;
  int bestj = 0;

  // ---- fp32 distance scan over 4 chunks of 128 codes ----
  for (int c0 = 0; c0 < kNE; c0 += kChunk) {
    __syncthreads();
    {
      const float4* src = (const float4*)(emb + (size_t)c0 * kED);
      #pragma unroll
      for (int i = 0; i < 8; ++i) {
        int q = i * kThreads + tid;
        int row = q >> 4;
        int c4  = (q & 15) << 2;
        float4 v = src[q];
        *(float4*)&etile[row][c4] = v;
      }
      if (tid < kChunk) se_t[tid] = se32[c0 + tid];
    }
    __syncthreads();

    #pragma unroll 2
    for (int i = 0; i < 16; ++i) {
      int jl0 = a + i * 8;
      int jl1 = jl0 + 4;
      const float* e0 = &etile[jl0][0];
      const float* e1 = &etile[jl1][0];
      float d00=0.f,d01=0.f,d02=0.f,d03=0.f;
      float d10=0.f,d11=0.f,d12=0.f,d13=0.f;
      #pragma unroll
      for (int dq = 0; dq < 16; ++dq) {
        float4 u = *(const float4*)&e0[dq*4];
        float4 w = *(const float4*)&e1[dq*4];
        d00 = __builtin_fmaf(fr[dq*4+0], u.x, d00);
        d01 = __builtin_fmaf(fr[dq*4+1], u.y, d01);
        d02 = __builtin_fmaf(fr[dq*4+2], u.z, d02);
        d03 = __builtin_fmaf(fr[dq*4+3], u.w, d03);
        d10 = __builtin_fmaf(fr[dq*4+0], w.x, d10);
        d11 = __builtin_fmaf(fr[dq*4+1], w.y, d11);
        d12 = __builtin_fmaf(fr[dq*4+2], w.z, d12);
        d13 = __builtin_fmaf(fr[dq*4+3], w.w, d13);
      }
      float dot0 = (d00 + d01) + (d02 + d03);
      float dot1 = (d10 + d11) + (d12 + d13);
      float dist0 = s_f + se_t[jl0] - 2.f * dot0;
      float dist1 = s_f + se_t[jl1] - 2.f * dot1;
      if (dist0 < best) { second = best; best = dist0; bestj = c0 + jl0; }
      else second = fminf(second, dist0);
      if (dist1 < best) { second = best; best = dist1; bestj = c0 + jl1; }
      else second = fminf(second, dist1);
    }
  }

  redv[tid] = best; redv2[tid] = second; redi[tid] = bestj;
  __syncthreads();

  // ---- merge 4 threads per token; flag near-ties for fp64 rescan ----
  if (tid < kTokPerBlk) {
    float bv = redv[tid*4]; int bj = redi[tid*4]; float sv = redv2[tid*4];
    #pragma unroll
    for (int t = 1; t < 4; ++t) {
      float v = redv[tid*4+t]; int j = redi[tid*4+t]; float s2 = redv2[tid*4+t];
      if (v < bv || (v == bv && j < bj)) {
        sv = fminf(fminf(bv, s2), sv);
        bv = v; bj = j;
      } else {
        sv = fminf(sv, fminf(v, s2));
      }
    }
    tok_idx[tid] = bj;
    if (sv - bv < kMargin) {
      int p = atomicAdd(&flag_cnt, 1);
      flag_list[p] = tid;
    }
  }
  __syncthreads();

  // ---- exact fp64 rescan for flagged tokens (rare; whole block cooperates) ----
  const int nflag = flag_cnt;
  for (int fi = 0; fi < nflag; ++fi) {
    const int tr = flag_list[fi];
    double db = 1e300; int dbj = 0;
    #pragma unroll 1
    for (int jj = 0; jj < 2; ++jj) {
      int j = tid * 2 + jj;
      const float* er = emb + (size_t)j * kED;
      double a0 = 0.0, a1 = 0.0, a2 = 0.0, a3 = 0.0;
      #pragma unroll
      for (int d = 0; d < kED; d += 4) {
        a0 = __builtin_fma((double)flat[tr][d+0], (double)er[d+0], a0);
        a1 = __builtin_fma((double)flat[tr][d+1], (double)er[d+1], a1);
        a2 = __builtin_fma((double)flat[tr][d+2], (double)er[d+2], a2);
        a3 = __builtin_fma((double)flat[tr][d+3], (double)er[d+3], a3);
      }
      double dist = se64[j] - 2.0 * ((a0 + a1) + (a2 + a3));
      if (dist < db || (dist == db && j < dbj)) { db = dist; dbj = j; }
    }
    redd[tid] = db; redj[tid] = dbj;
    __syncthreads();
    for (int s2 = kThreads / 2; s2 > 0; s2 >>= 1) {
      if (tid < s2) {
        double v = redd[tid + s2]; int j = redj[tid + s2];
        if (v < redd[tid] || (v == redd[tid] && j < redj[tid])) {
          redd[tid] = v; redj[tid] = j;
        }
      }
      __syncthreads();
    }
    if (tid == 0) tok_idx[tr] = redj[0];
    __syncthreads();
  }

  // ---- publish token assignments (consumed by vq_dw) ----
  if (tid < kTokPerBlk) idx_out[token_base + tid] = tok_idx[tid];

  // ---- encodings one-hot: write computed values directly ----
  {
    float2* encb2 = (float2*)(enc + (size_t)token_base * kNE);
    #pragma unroll 4
    for (int i = 0; i < 64; ++i) {
      int q = i * kThreads + tid;   // float2 idx, 0..16383
      int row = q >> 8;
      int c2  = (q & 255) * 2;
      int bi = tok_idx[row];
      float2 v;
      v.x = (bi == c2)     ? 1.f : 0.f;
      v.y = (bi == c2 + 1) ? 1.f : 0.f;
      encb2[q] = v;
    }
  }

  // ---- gather assigned code rows into LDS (reuse etile) ----
  float* qt = &etile[0][0];   // [64][65] overlay
  {
    int rr = tid >> 2;
    int c0 = (tid & 3) * 16;
    const float* er = emb + (size_t)tok_idx[rr] * kED;
    #pragma unroll
    for (int i = 0; i < 16; ++i) qt[rr * 65 + c0 + i] = er[c0 + i];
  }
  __syncthreads();

  // ---- quantized_st output (coalesced NCHW) + commitment loss ----
  float lacc = 0.f;
  {
    float* outb = out_q + (size_t)batch * kED * kHW + pos0;
    const int p  = tid & 63;
    const int c0 = tid >> 6;
    #pragma unroll
    for (int i = 0; i < 16; ++i) {
      int c = i * 4 + c0;
      float inv  = flat[p][c];
      float qv   = qt[p * 65 + c];
      float diff = qv - inv;
      outb[(size_t)c * kHW + p] = inv + diff;
      lacc = __builtin_fmaf(diff, diff, lacc);
    }
  }
  #pragma unroll
  for (int off = 32; off > 0; off >>= 1) lacc += __shfl_down(lacc, off, 64);
  if ((tid & 63) == 0) atomicAdd(loss_sum, lacc);
}

// Per-block private dw accumulator in LDS; no global atomics.
extern "C" __global__ __launch_bounds__(kThreads) void vq_dw(
    const float* __restrict__ x, const int* __restrict__ idx,
    float* __restrict__ part, int G) {
  __shared__ float dwacc[kNE * kED];   // 131072 B
  __shared__ int   hist[kNE];
  __shared__ float flat[kTokPerBlk][65];
  __shared__ int   idxs[kTokPerBlk];

  const int tid = threadIdx.x;
  // zero accumulators
  #pragma unroll
  for (int i = 0; i < kNE * kED / kThreads; ++i) dwacc[i * kThreads + tid] = 0.f;
  for (int i = tid; i < kNE; i += kThreads) hist[i] = 0;
  __syncthreads();

  for (int tile = blockIdx.x; tile < kNTiles; tile += G) {
    const int token_base = tile * kTokPerBlk;
    const int batch = token_base / kHW;
    const int pos0  = token_base % kHW;
    const float* xb = x + (size_t)batch * kED * kHW + pos0;
    {
      const int p  = tid & 63;
      const int d0 = tid >> 6;
      #pragma unroll
      for (int i = 0; i < 16; ++i) {
        int d = i * 4 + d0;
        flat[p][d] = xb[(size_t)d * kHW + p];
      }
    }
    if (tid < kTokPerBlk) idxs[tid] = idx[token_base + tid];
    __syncthreads();

    // wave w handles tokens w, w+4, ... (one ds_add_f32 wave-instr per token)
    {
      const int w = tid >> 6;
      const int d = tid & 63;
      #pragma unroll
      for (int i = 0; i < 16; ++i) {
        int rr = w + i * 4;
        atomicAdd(&dwacc[idxs[rr] * kED + d], flat[rr][d]);
      }
    }
    if (tid < kTokPerBlk) atomicAdd(&hist[idxs[tid]], 1);
    __syncthreads();
  }

  // write dense partial (coalesced)
  float* dst = part + (size_t)blockIdx.x * kPartStride;
  #pragma unroll
  for (int i = 0; i < kNE * kED / kThreads / 4; ++i) {
    int q = i * kThreads + tid;
    *(float4*)&dst[q * 4] = *(float4*)&dwacc[q * 4];
  }
  #pragma unroll
  for (int i = 0; i < kNE / kThreads; ++i) {
    int q = i * kThreads + tid;
    dst[kNE * kED + q] = (float)hist[q];
  }
}

// Deterministic dense reduction of G partials -> dw + counts.
extern "C" __global__ void vq_red(const float* __restrict__ part,
                                  float* __restrict__ dwf,
                                  float* __restrict__ cnt, int G) {
  int i = blockIdx.x * blockDim.x + threadIdx.x;
  if (i >= kPartStride) return;
  float s0 = 0.f, s1 = 0.f, s2 = 0.f, s3 = 0.f;
  int p = 0;
  for (; p + 3 < G; p += 4) {
    s0 += part[(size_t)(p + 0) * kPartStride + i];
    s1 += part[(size_t)(p + 1) * kPartStride + i];
    s2 += part[(size_t)(p + 2) * kPartStride + i];
    s3 += part[(size_t)(p + 3) * kPartStride + i];
  }
  for (; p < G; ++p) s0 += part[(size_t)p * kPartStride + i];
  float s = (s0 + s1) + (s2 + s3);
  if (i < kNE * kED) dwf[i] = s;
  else cnt[i - kNE * kED] = s;
}

// Fallback when ws too small: global atomics (slow but correct).
extern "C" __global__ __launch_bounds__(kThreads) void vq_dw_atomic(
    const float* __restrict__ x, const int* __restrict__ idx,
    float* __restrict__ dwf, float* __restrict__ cnt) {
  __shared__ float flat[kTokPerBlk][65];
  __shared__ int   idxs[kTokPerBlk];
  const int tid = threadIdx.x;
  const int token_base = blockIdx.x * kTokPerBlk;
  const int batch = token_base / kHW;
  const int pos0  = token_base % kHW;
  const float* xb = x + (size_t)batch * kED * kHW + pos0;
  {
    const int p  = tid & 63;
    const int d0 = tid >> 6;
    #pragma unroll
    for (int i = 0; i < 16; ++i) {
      int d = i * 4 + d0;
      flat[p][d] = xb[(size_t)d * kHW + p];
    }
  }
  if (tid < kTokPerBlk) idxs[tid] = idx[token_base + tid];
  __syncthreads();
  {
    int rr = tid >> 2;
    int c0 = (tid & 3) * 16;
    float* dwr = dwf + (size_t)idxs[rr] * kED;
    #pragma unroll
    for (int i = 0; i < 16; ++i) atomicAdd(&dwr[c0 + i], flat[rr][c0 + i]);
  }
  if (tid < kTokPerBlk) atomicAdd(&cnt[idxs[tid]], 1.0f);
}

// cluster Laplace smoothing, perplexity, loss
extern "C" __global__ void vq_fin_a(const float* __restrict__ ema_cs,
                                    const float* __restrict__ counts,
                                    const float* __restrict__ loss_sum,
                                    float* __restrict__ out) {
  __shared__ float red[kNE];
  const int j = threadIdx.x;
  float craw = ema_cs[j] * 0.99f + 0.01f * counts[j];
  red[j] = craw;
  __syncthreads();
  for (int s = kNE / 2; s > 0; s >>= 1) {
    if (j < s) red[j] += red[j + s];
    __syncthreads();
  }
  float k = red[0];
  __syncthreads();
  float clu = (craw + 1e-5f) / (k + kNE * 1e-5f) * k;
  out[O_CLUSTER + j] = clu;
  float avg = counts[j] * (1.0f / 131072.0f);
  float term = avg * logf(avg + 1e-10f);
  red[j] = term;
  __syncthreads();
  for (int s = kNE / 2; s > 0; s >>= 1) {
    if (j < s) red[j] += red[j + s];
    __syncthreads();
  }
  if (j == 0) {
    out[O_PERP] = expf(-red[0]);
    out[O_LOSS] = 0.25f * loss_sum[0] * (1.0f / 8388608.0f);
  }
}

// new_ema_w and new_embedding
extern "C" __global__ void vq_fin_b(const float* __restrict__ ema_w,
                                    const float* __restrict__ dw,
                                    const float* __restrict__ out_cluster,
                                    float* __restrict__ out) {
  int i = blockIdx.x * blockDim.x + threadIdx.x;   // 0..32767
  int j = i >> 6;
  float nw = ema_w[i] * 0.99f + 0.01f * dw[i];
  out[O_NEWEMAW + i] = nw;
  out[O_NEWEMB + i] = nw / out_cluster[j];
}

extern "C" void kernel_launch(void* const* d_in, const int* in_sizes, int n_in,
                              void* d_out, int out_size, void* d_ws, size_t ws_size,
                              hipStream_t stream) {
  const float* x      = (const float*)d_in[0];
  const float* emb    = (const float*)d_in[1];
  const float* ema_w  = (const float*)d_in[2];
  const float* ema_cs = (const float*)d_in[3];
  float* out = (float*)d_out;
  float* ws  = (float*)d_ws;

  int*    idxb     = (int*)d_ws;
  float*  loss_sum = ws + W_LOSS;
  float*  se32     = ws + W_SE32;
  double* se64     = (double*)(ws + W_SE64);
  float*  cnt      = ws + W_CNT;
  float*  dwf      = ws + W_DW;
  float*  part     = ws + W_PART;

  // how many dw partials fit in ws?
  long avail = (long)(ws_size / 4) - (long)W_PART;
  int G = avail > 0 ? (int)(avail / kPartStride) : 0;
  if (G > 256) G = 256;
  const bool fallback = (G < 8);

  // zero loss + final cnt/dw region (cnt/dw needed zeroed only for fallback)
  hipMemsetAsync(ws + W_LOSS, 0, sizeof(float), stream);
  hipMemsetAsync(ws + W_CNT, 0, (kNE + kNE * kED) * sizeof(float), stream);

  hipLaunchKernelGGL(vq_se, dim3(2), dim3(256), 0, stream, emb, se32, se64);
  hipLaunchKernelGGL(vq_main, dim3(kNTiles), dim3(kThreads), 0, stream,
                     x, emb, se32, se64, out + O_OUT, out + O_ENC,
                     idxb, loss_sum);
  if (fallback) {
    hipLaunchKernelGGL(vq_dw_atomic, dim3(kNTiles), dim3(kThreads), 0, stream,
                       x, idxb, dwf, cnt);
  } else {
    hipLaunchKernelGGL(vq_dw, dim3(G), dim3(kThreads), 0, stream,
                       x, idxb, part, G);
    hipLaunchKernelGGL(vq_red, dim3((kPartStride + 255) / 256), dim3(256), 0,
                       stream, part, dwf, cnt, G);
  }
  hipLaunchKernelGGL(vq_fin_a, dim3(1), dim3(kNE), 0, stream,
                     ema_cs, cnt, loss_sum, out);
  hipLaunchKernelGGL(vq_fin_b, dim3(32768 / 256), dim3(256), 0, stream,
                     ema_w, dwf, out + O_CLUSTER, out);
}